// Round 1
// baseline (157.905 us; speedup 1.0000x reference)
//
#include <hip/hip_runtime.h>

typedef __attribute__((ext_vector_type(8))) short bf16x8;
typedef __attribute__((ext_vector_type(4))) float f32x4;
typedef __attribute__((ext_vector_type(4))) unsigned short u16x4;
typedef __attribute__((ext_vector_type(8))) unsigned short u16x8;

#define B_ 2048
#define A_ 50
#define H_ 512
#define NACT_ 64
#define F_ 562
#define BM_ 128
#define BK_ 32
#define NSTEP_ (H_ / BK_) /* 16 */
#define W1LD_ (BK_ + 8)   /* 40 ushorts per LDS row (pad -> 2-way max) */
#define HLD_ (H_ + 8)     /* 520 */

// ws layout (bytes)
#define WS_W1T 0
#define WS_W2T ((size_t)A_ * H_ * H_ * 2)                    /* 26,214,400 */
#define WS_B1 (WS_W2T + (size_t)A_ * NACT_ * H_ * 2)         /* 29,491,200 */
#define WS_B2 (WS_B1 + (size_t)A_ * H_ * 4)                  /* 29,593,600 */

static __device__ __forceinline__ unsigned short f2bf(float f) {
  unsigned int u = __builtin_bit_cast(unsigned int, f);
  u += 0x7fffu + ((u >> 16) & 1u);
  return (unsigned short)(u >> 16);
}

static __device__ __forceinline__ void gld_lds16(const unsigned short* src,
                                                 unsigned short* dst) {
  __builtin_amdgcn_global_load_lds(
      (const __attribute__((address_space(1))) unsigned int*)(const void*)src,
      (__attribute__((address_space(3))) unsigned int*)(void*)dst, 16, 0, 0);
}

static __device__ __forceinline__ int clamp_r(int r) {
  return r < 0 ? 0 : (r > A_ - 1 ? A_ - 1 : r);
}

// W1T[a][j][k] = bf16(W1[r_a][k][j]), j,k < 512 (transpose per agent)
__global__ void prep_w1(const float* __restrict__ w1,
                        const int* __restrict__ routing,
                        unsigned short* __restrict__ w1t) {
  const int bid = blockIdx.x;
  const int a = bid / 64;
  const int tile = bid - a * 64;
  const int tk = tile & 7, tj = tile >> 3;
  const int k0 = tk * 64, j0 = tj * 64;
  const int r = clamp_r(routing[a]);
  __shared__ float tl[64][65];
  const int t = threadIdx.x;
  const int c = t & 63, q = t >> 6;
#pragma unroll
  for (int i = 0; i < 16; ++i) {
    const int kl = q + i * 4;
    tl[kl][c] = w1[((size_t)r * F_ + k0 + kl) * H_ + j0 + c];
  }
  __syncthreads();
#pragma unroll
  for (int i = 0; i < 16; ++i) {
    const int jl = q + i * 4;
    w1t[((size_t)a * H_ + j0 + jl) * H_ + k0 + c] = f2bf(tl[c][jl]);
  }
}

// W2T[a][n][k] = bf16(W2[r_a][k][n])
__global__ void prep_w2(const float* __restrict__ w2,
                        const int* __restrict__ routing,
                        unsigned short* __restrict__ w2t) {
  const int bid = blockIdx.x;
  const int a = bid >> 3;
  const int tk = bid & 7;
  const int k0 = tk * 64;
  const int r = clamp_r(routing[a]);
  __shared__ float tl[64][65];
  const int t = threadIdx.x;
  const int c = t & 63, q = t >> 6;
#pragma unroll
  for (int i = 0; i < 16; ++i) {
    const int kl = q + i * 4;
    tl[kl][c] = w2[((size_t)r * H_ + k0 + kl) * NACT_ + c];
  }
  __syncthreads();
#pragma unroll
  for (int i = 0; i < 16; ++i) {
    const int nl = q + i * 4;
    w2t[((size_t)a * NACT_ + nl) * H_ + k0 + c] = f2bf(tl[c][nl]);
  }
}

// bias1_eff[a][j] = b1[r][j] + W1[r][H+a][j] (onehot fold); bias2_eff[a][n]
__global__ void prep_bias(const float* __restrict__ w1,
                          const float* __restrict__ b1,
                          const float* __restrict__ b2,
                          const int* __restrict__ routing,
                          float* __restrict__ bias1, float* __restrict__ bias2) {
  const int a = blockIdx.x;
  const int t = threadIdx.x;
  const int r = clamp_r(routing[a]);
  bias1[a * H_ + t] = b1[(size_t)r * H_ + t] + w1[((size_t)r * F_ + H_ + a) * H_ + t];
  if (t < NACT_) bias2[a * NACT_ + t] = b2[r * NACT_ + t];
}

__global__ __launch_bounds__(512, 2) void divtree_main(
    const float* __restrict__ x, const unsigned short* __restrict__ w1t,
    const unsigned short* __restrict__ w2t, const float* __restrict__ bias1,
    const float* __restrict__ bias2, float* __restrict__ out) {
  __shared__ union {
    struct {
      unsigned short w1[2][H_ * W1LD_];  // 2 x 40 KiB
      unsigned short xs[2][BM_ * W1LD_]; // 2 x 10 KiB
    } st;
    unsigned short h[BM_ * HLD_]; // 130 KiB (reused after K-loop)
  } sm;

  // XCD-bijective swizzle: 800 blocks, 800 % 8 == 0 -> cpx = 100
  const int bid = blockIdx.x;
  const int swz = (bid & 7) * 100 + (bid >> 3);
  const int a = swz >> 4;    // agent
  const int mblk = swz & 15; // M tile
  const int b0 = mblk * BM_;

  const int tid = threadIdx.x;
  const int lane = tid & 63;
  const int w = tid >> 6; // wave 0..7
  const int l16 = lane & 15;
  const int lk = lane >> 4; // 0..3

  // layer-1 wave tile: 128(j) x 64(m); wave grid 4(j) x 2(m)
  const int wj = (w & 3) * 128;
  const int wm = (w >> 2) * 64;

  const unsigned short* w1ta = w1t + (size_t)a * H_ * H_;

  // X staging: thread -> (row, 8-float k-slice)
  const int xrow = tid >> 2;
  const int xc = (tid & 3) * 8;
  const float* xbase =
      x + ((size_t)b0 * A_ + (size_t)a) * H_ + (size_t)xrow * (A_ * H_) + xc;

  f32x4 acc[8][4];
#pragma unroll
  for (int i = 0; i < 8; ++i)
#pragma unroll
    for (int j = 0; j < 4; ++j) acc[i][j] = (f32x4){0.f, 0.f, 0.f, 0.f};

  f32x4 xv0, xv1;

  // prologue: stage t=0 into buf 0
  {
    xv0 = *(const f32x4*)(xbase);
    xv1 = *(const f32x4*)(xbase + 4);
#pragma unroll
    for (int i = 0; i < 5; ++i) {
      const int chunk = i * 512 + tid;
      const int j = chunk / 5;
      const int part = chunk - j * 5;
      const unsigned short* src =
          (part < 4) ? (w1ta + (size_t)j * H_ + part * 8) : w1ta;
      unsigned short* dst = sm.st.w1[0] + (size_t)(i * 512 + (w << 6)) * 8;
      gld_lds16(src, dst);
    }
    u16x8 v;
#pragma unroll
    for (int e = 0; e < 4; ++e) v[e] = f2bf(xv0[e]);
#pragma unroll
    for (int e = 0; e < 4; ++e) v[4 + e] = f2bf(xv1[e]);
    *(u16x8*)(sm.st.xs[0] + xrow * W1LD_ + xc) = v;
  }
  __syncthreads();

  int cur = 0;
  for (int t = 0; t < NSTEP_; ++t) {
    const bool pf = (t + 1 < NSTEP_);
    if (pf) { // issue next-tile loads early (T14: write-late after compute)
      const float* p = xbase + (t + 1) * BK_;
      xv0 = *(const f32x4*)p;
      xv1 = *(const f32x4*)(p + 4);
      const int k0 = (t + 1) * BK_;
#pragma unroll
      for (int i = 0; i < 5; ++i) {
        const int chunk = i * 512 + tid;
        const int j = chunk / 5;
        const int part = chunk - j * 5;
        const unsigned short* src =
            (part < 4) ? (w1ta + (size_t)j * H_ + k0 + part * 8) : w1ta;
        unsigned short* dst =
            sm.st.w1[cur ^ 1] + (size_t)(i * 512 + (w << 6)) * 8;
        gld_lds16(src, dst);
      }
    }
    // compute current tile: D[j][m] = W1T(j,k) * x(m,k)^T  (swapped operands)
    const unsigned short* w1s = sm.st.w1[cur];
    const unsigned short* xss = sm.st.xs[cur];
    bf16x8 afr[8], bfr[4];
#pragma unroll
    for (int jf = 0; jf < 8; ++jf)
      afr[jf] = *(const bf16x8*)(w1s + (wj + jf * 16 + l16) * W1LD_ + lk * 8);
#pragma unroll
    for (int mf = 0; mf < 4; ++mf)
      bfr[mf] = *(const bf16x8*)(xss + (wm + mf * 16 + l16) * W1LD_ + lk * 8);
#pragma unroll
    for (int jf = 0; jf < 8; ++jf)
#pragma unroll
      for (int mf = 0; mf < 4; ++mf)
        acc[jf][mf] = __builtin_amdgcn_mfma_f32_16x16x32_bf16(
            afr[jf], bfr[mf], acc[jf][mf], 0, 0, 0);
    if (pf) { // late LDS write of prefetched X (hides HBM latency under MFMA)
      u16x8 v;
#pragma unroll
      for (int e = 0; e < 4; ++e) v[e] = f2bf(xv0[e]);
#pragma unroll
      for (int e = 0; e < 4; ++e) v[4 + e] = f2bf(xv1[e]);
      *(u16x8*)(sm.st.xs[cur ^ 1] + xrow * W1LD_ + xc) = v;
    }
    __syncthreads();
    cur ^= 1;
  }

  // h = relu(acc + bias1_eff) -> LDS bf16; lane holds 4 consecutive j -> b64
  const float* b1p = bias1 + a * H_;
#pragma unroll
  for (int jf = 0; jf < 8; ++jf) {
    const f32x4 bv = *(const f32x4*)(b1p + wj + jf * 16 + lk * 4);
#pragma unroll
    for (int mf = 0; mf < 4; ++mf) {
      u16x4 hv;
#pragma unroll
      for (int r = 0; r < 4; ++r) {
        float f = acc[jf][mf][r] + bv[r];
        f = f > 0.f ? f : 0.f;
        hv[r] = f2bf(f);
      }
      const int m = wm + mf * 16 + l16;
      const int j0 = wj + jf * 16 + lk * 4;
      *(u16x4*)(sm.h + (size_t)m * HLD_ + j0) = hv;
    }
  }
  __syncthreads();

  // layer 2: out[m][n] = h(m,k) * W2T(n,k)^T ; wave tile 64(m) x 16(n)
  const int n2 = (w & 3) * 16;
  const int m2 = (w >> 2) * 64;
  const unsigned short* w2p =
      w2t + ((size_t)a * NACT_ + n2 + l16) * H_ + lk * 8;
  f32x4 acc2[4];
#pragma unroll
  for (int mf = 0; mf < 4; ++mf) acc2[mf] = (f32x4){0.f, 0.f, 0.f, 0.f};
#pragma unroll
  for (int ks = 0; ks < 16; ++ks) {
    const bf16x8 bf2 = *(const bf16x8*)(w2p + ks * 32);
#pragma unroll
    for (int mf = 0; mf < 4; ++mf) {
      const bf16x8 af2 = *(const bf16x8*)(
          sm.h + (size_t)(m2 + mf * 16 + l16) * HLD_ + ks * 32 + lk * 8);
      acc2[mf] = __builtin_amdgcn_mfma_f32_16x16x32_bf16(af2, bf2, acc2[mf],
                                                         0, 0, 0);
    }
  }
  const float b2v = bias2[a * NACT_ + n2 + l16];
#pragma unroll
  for (int mf = 0; mf < 4; ++mf)
#pragma unroll
    for (int r = 0; r < 4; ++r) {
      const int m = m2 + mf * 16 + lk * 4 + r;
      out[((size_t)(b0 + m) * A_ + a) * NACT_ + n2 + l16] = acc2[mf][r] + b2v;
    }
}

extern "C" void kernel_launch(void* const* d_in, const int* in_sizes, int n_in,
                              void* d_out, int out_size, void* d_ws,
                              size_t ws_size, hipStream_t stream) {
  const float* x = (const float*)d_in[0];
  const float* w1 = (const float*)d_in[1];
  const float* b1 = (const float*)d_in[2];
  const float* w2 = (const float*)d_in[3];
  const float* b2 = (const float*)d_in[4];
  const int* routing = (const int*)d_in[5];
  float* out = (float*)d_out;

  char* ws = (char*)d_ws;
  unsigned short* w1t = (unsigned short*)(ws + WS_W1T);
  unsigned short* w2t = (unsigned short*)(ws + WS_W2T);
  float* bias1 = (float*)(ws + WS_B1);
  float* bias2 = (float*)(ws + WS_B2);

  prep_w1<<<A_ * 64, 256, 0, stream>>>(w1, routing, w1t);
  prep_w2<<<A_ * 8, 256, 0, stream>>>(w2, routing, w2t);
  prep_bias<<<A_, 512, 0, stream>>>(w1, b1, b2, routing, bias1, bias2);
  divtree_main<<<A_ * (B_ / BM_), 512, 0, stream>>>(x, w1t, w2t, bias1, bias2,
                                                    out);
}

// Round 2
// 153.198 us; speedup vs baseline: 1.0307x; 1.0307x over previous
//
#include <hip/hip_runtime.h>

typedef __attribute__((ext_vector_type(8))) short bf16x8;
typedef __attribute__((ext_vector_type(4))) float f32x4;
typedef __attribute__((ext_vector_type(4))) unsigned short u16x4;

#define B_ 2048
#define A_ 50
#define H_ 512
#define NACT_ 64
#define F_ 562
#define BM_ 64
#define BK_ 32
#define NSTEP_ (H_ / BK_) /* 16 */

// ws layout (bytes)
#define WS_W1T 0
#define WS_W2T ((size_t)A_ * H_ * H_ * 2)                    /* 26,214,400 */
#define WS_B1 (WS_W2T + (size_t)A_ * NACT_ * H_ * 2)         /* 29,491,200 */
#define WS_B2 (WS_B1 + (size_t)A_ * H_ * 4)                  /* 29,593,600 */

static __device__ __forceinline__ unsigned short f2bf(float f) {
  unsigned int u = __builtin_bit_cast(unsigned int, f);
  u += 0x7fffu + ((u >> 16) & 1u);
  return (unsigned short)(u >> 16);
}

static __device__ __forceinline__ void gld_lds16(const unsigned short* src,
                                                 unsigned short* dst) {
  __builtin_amdgcn_global_load_lds(
      (const __attribute__((address_space(1))) unsigned int*)(const void*)src,
      (__attribute__((address_space(3))) unsigned int*)(void*)dst, 16, 0, 0);
}

static __device__ __forceinline__ int clamp_r(int r) {
  return r < 0 ? 0 : (r > A_ - 1 ? A_ - 1 : r);
}

// W1T step-tiled + pre-swizzled: value (a, j, k) with t=k>>5, k32=k&31,
// sub=(k>>3)&3, elem=k&7 stored at
//   ((a*16 + t)*512 + j)*32 + (sub ^ (j&3))*8 + elem.
// Each (a,t) slab is a contiguous 32 KiB chunk -> coalesced global_load_lds
// with LINEAR LDS dest; ds_read_b128 of an A-fragment applies the same
// sub^(row&3) XOR -> even bank spread (b128 floor), no padding needed.
__global__ void prep_w1(const float* __restrict__ w1,
                        const int* __restrict__ routing,
                        unsigned short* __restrict__ w1t) {
  const int bid = blockIdx.x;
  const int a = bid / 64;
  const int tile = bid - a * 64;
  const int tk = tile & 7, tj = tile >> 3;
  const int k0 = tk * 64, j0 = tj * 64;
  const int r = clamp_r(routing[a]);
  __shared__ float tl[64][65];
  const int t = threadIdx.x;
  const int c = t & 63, q = t >> 6;
#pragma unroll
  for (int i = 0; i < 16; ++i) {
    const int kl = q + i * 4;
    tl[kl][c] = w1[((size_t)r * F_ + k0 + kl) * H_ + j0 + c];
  }
  __syncthreads();
#pragma unroll
  for (int i = 0; i < 16; ++i) {
    const int jl = q + i * 4;
    const int j = j0 + jl;
    const int k = k0 + c;
    const int ts = k >> 5;
    const int sub = (k >> 3) & 3;
    const int elem = k & 7;
    const size_t idx = (((size_t)a * 16 + ts) * H_ + j) * 32 +
                       (size_t)((sub ^ (j & 3)) * 8 + elem);
    w1t[idx] = f2bf(tl[c][jl]);
  }
}

// W2T[a][n][k] = bf16(W2[r_a][k][n])  (k-contiguous rows, unchanged)
__global__ void prep_w2(const float* __restrict__ w2,
                        const int* __restrict__ routing,
                        unsigned short* __restrict__ w2t) {
  const int bid = blockIdx.x;
  const int a = bid >> 3;
  const int tk = bid & 7;
  const int k0 = tk * 64;
  const int r = clamp_r(routing[a]);
  __shared__ float tl[64][65];
  const int t = threadIdx.x;
  const int c = t & 63, q = t >> 6;
#pragma unroll
  for (int i = 0; i < 16; ++i) {
    const int kl = q + i * 4;
    tl[kl][c] = w2[((size_t)r * H_ + k0 + kl) * NACT_ + c];
  }
  __syncthreads();
#pragma unroll
  for (int i = 0; i < 16; ++i) {
    const int nl = q + i * 4;
    w2t[((size_t)a * NACT_ + nl) * H_ + k0 + c] = f2bf(tl[c][nl]);
  }
}

__global__ void prep_bias(const float* __restrict__ w1,
                          const float* __restrict__ b1,
                          const float* __restrict__ b2,
                          const int* __restrict__ routing,
                          float* __restrict__ bias1, float* __restrict__ bias2) {
  const int a = blockIdx.x;
  const int t = threadIdx.x;
  const int r = clamp_r(routing[a]);
  bias1[a * H_ + t] = b1[(size_t)r * H_ + t] + w1[((size_t)r * F_ + H_ + a) * H_ + t];
  if (t < NACT_) bias2[a * NACT_ + t] = b2[r * NACT_ + t];
}

__global__ __launch_bounds__(512, 4) void divtree_main(
    const float* __restrict__ x, const unsigned short* __restrict__ w1t,
    const unsigned short* __restrict__ w2t, const float* __restrict__ bias1,
    const float* __restrict__ bias2, float* __restrict__ out) {
  __shared__ union {
    struct {
      unsigned short w1[2][H_ * BK_];   // 2 x 32 KiB, linear (pre-swizzled)
      unsigned short xs[2][BM_ * BK_];  // 2 x 4 KiB, swizzled rows
    } st;                               // 72 KiB
    unsigned short h[BM_ * H_];         // 64 KiB, XOR-swizzled
  } sm;

  // XCD-bijective swizzle: 1600 blocks, 1600 % 8 == 0 -> cpx = 200
  const int bid = blockIdx.x;
  const int swz = (bid & 7) * 200 + (bid >> 3);
  const int a = swz >> 5;    // agent (0..49)
  const int mblk = swz & 31; // M tile (0..31)
  const int b0 = mblk * BM_;

  const int tid = threadIdx.x;
  const int lane = tid & 63;
  const int w = tid >> 6; // wave 0..7
  const int l16 = lane & 15;
  const int lk = lane >> 4; // 0..3
  const int sxor = lk ^ (l16 & 3); // fragment-read chunk XOR (row&3 == l16&3)

  // layer-1 wave tile: 64(j) x 64(m); 8 waves cover j=512, all share m 0..63
  const int wj = w * 64;

  const unsigned short* w1ta = w1t + (size_t)a * (H_ * H_); // 512 KiB/agent

  // X staging: thread -> (row = tid>>3, 4-float k-slice at (tid&7)*4)
  const int xrow = tid >> 3;
  const int xq = tid & 7;
  const float* xbase =
      x + ((size_t)(b0 + xrow) * A_ + (size_t)a) * H_ + (size_t)xq * 4;
  // xs LDS write offset (swizzled): c = xq>>1, half = xq&1
  const int xs_off = xrow * BK_ + ((xq >> 1) ^ (xrow & 3)) * 8 + (xq & 1) * 4;

  // per-wave fragment LDS offsets (ushort units)
  // afr row = wj + jf*16 + l16, chunk = sxor : off = row*32 + sxor*8
  const int afr_base = (wj + l16) * BK_ + sxor * 8;
  // bfr row = mf*16 + l16
  const int bfr_base = l16 * BK_ + sxor * 8;

  f32x4 acc[4][4];
#pragma unroll
  for (int i = 0; i < 4; ++i)
#pragma unroll
    for (int j = 0; j < 4; ++j) acc[i][j] = (f32x4){0.f, 0.f, 0.f, 0.f};

  f32x4 xv;

  // prologue: stage t=0 into buf 0
  {
    xv = *(const f32x4*)(xbase);
#pragma unroll
    for (int i = 0; i < 4; ++i) { // 2048 chunks of 16B = 32 KiB
      const unsigned short* src = w1ta + ((size_t)(i * 512 + tid) << 3);
      unsigned short* dst = sm.st.w1[0] + (size_t)(i * 512 + (w << 6)) * 8;
      gld_lds16(src, dst);
    }
    u16x4 v;
#pragma unroll
    for (int e = 0; e < 4; ++e) v[e] = f2bf(xv[e]);
    *(u16x4*)(sm.st.xs[0] + xs_off) = v;
  }
  __syncthreads();

  int cur = 0;
  for (int t = 0; t < NSTEP_; ++t) {
    const bool pf = (t + 1 < NSTEP_);
    if (pf) { // issue next-tile loads early (T14 split)
      xv = *(const f32x4*)(xbase + (t + 1) * BK_);
      const unsigned short* wsrc = w1ta + (size_t)(t + 1) * (H_ * BK_);
#pragma unroll
      for (int i = 0; i < 4; ++i) {
        const unsigned short* src = wsrc + ((size_t)(i * 512 + tid) << 3);
        unsigned short* dst =
            sm.st.w1[cur ^ 1] + (size_t)(i * 512 + (w << 6)) * 8;
        gld_lds16(src, dst);
      }
    }
    // compute current tile: D[j][m] = W1T(j,k) * x(m,k)^T
    const unsigned short* w1s = sm.st.w1[cur];
    const unsigned short* xss = sm.st.xs[cur];
    bf16x8 afr[4], bfr[4];
#pragma unroll
    for (int jf = 0; jf < 4; ++jf)
      afr[jf] = *(const bf16x8*)(w1s + afr_base + jf * (16 * BK_));
#pragma unroll
    for (int mf = 0; mf < 4; ++mf)
      bfr[mf] = *(const bf16x8*)(xss + bfr_base + mf * (16 * BK_));
#pragma unroll
    for (int jf = 0; jf < 4; ++jf)
#pragma unroll
      for (int mf = 0; mf < 4; ++mf)
        acc[jf][mf] = __builtin_amdgcn_mfma_f32_16x16x32_bf16(
            afr[jf], bfr[mf], acc[jf][mf], 0, 0, 0);
    if (pf) { // late LDS write of prefetched X
      u16x4 v;
#pragma unroll
      for (int e = 0; e < 4; ++e) v[e] = f2bf(xv[e]);
      *(u16x4*)(sm.st.xs[cur ^ 1] + xs_off) = v;
    }
    __syncthreads();
    cur ^= 1;
  }

  // h = relu(acc + bias1_eff) -> LDS bf16, XOR-swizzled rows (T2)
  // write granule u16x4 at j0 = wj + jf*16 + lk*4:
  //   c = wj/8 + jf*2 + (lk>>1); half = lk&1; c' = c ^ (m&7) (m&7 == l16&7)
  const float* b1p = bias1 + a * H_;
#pragma unroll
  for (int jf = 0; jf < 4; ++jf) {
    const f32x4 bv = *(const f32x4*)(b1p + wj + jf * 16 + lk * 4);
    const int cbase = (wj >> 3) + jf * 2 + (lk >> 1);
    const int half4 = (lk & 1) * 4;
#pragma unroll
    for (int mf = 0; mf < 4; ++mf) {
      u16x4 hv;
#pragma unroll
      for (int r = 0; r < 4; ++r) {
        float f = acc[jf][mf][r] + bv[r];
        f = f > 0.f ? f : 0.f;
        hv[r] = f2bf(f);
      }
      const int m = mf * 16 + l16;
      const int off = m * H_ + (cbase ^ (l16 & 7)) * 8 + half4;
      *(u16x4*)(sm.h + off) = hv;
    }
  }
  __syncthreads();

  // layer 2: out[m][n] = h(m,k) * W2T(n,k)^T ; wave tile 32(m) x 16(n)
  const int m0 = (w & 1) * 32;
  const int n0 = (w >> 1) * 16;
  const unsigned short* w2p =
      w2t + ((size_t)a * NACT_ + n0 + l16) * H_ + lk * 8;
  f32x4 acc2[2];
  acc2[0] = (f32x4){0.f, 0.f, 0.f, 0.f};
  acc2[1] = (f32x4){0.f, 0.f, 0.f, 0.f};
#pragma unroll
  for (int kf = 0; kf < 16; ++kf) {
    const bf16x8 bf2 = *(const bf16x8*)(w2p + kf * 32);
#pragma unroll
    for (int mf = 0; mf < 2; ++mf) {
      const int row = m0 + mf * 16 + l16;
      // h read: c = kf*4 + lk, c' = c ^ (row&7); row&7 == l16&7
      const int off = row * H_ + (((kf * 4 + lk) ^ (l16 & 7))) * 8;
      const bf16x8 af2 = *(const bf16x8*)(sm.h + off);
      acc2[mf] = __builtin_amdgcn_mfma_f32_16x16x32_bf16(af2, bf2, acc2[mf],
                                                         0, 0, 0);
    }
  }
  const float b2v = bias2[a * NACT_ + n0 + l16];
#pragma unroll
  for (int mf = 0; mf < 2; ++mf)
#pragma unroll
    for (int r = 0; r < 4; ++r) {
      const int m = m0 + mf * 16 + lk * 4 + r;
      out[((size_t)(b0 + m) * A_ + a) * NACT_ + n0 + l16] = acc2[mf][r] + b2v;
    }
}

extern "C" void kernel_launch(void* const* d_in, const int* in_sizes, int n_in,
                              void* d_out, int out_size, void* d_ws,
                              size_t ws_size, hipStream_t stream) {
  const float* x = (const float*)d_in[0];
  const float* w1 = (const float*)d_in[1];
  const float* b1 = (const float*)d_in[2];
  const float* w2 = (const float*)d_in[3];
  const float* b2 = (const float*)d_in[4];
  const int* routing = (const int*)d_in[5];
  float* out = (float*)d_out;

  char* ws = (char*)d_ws;
  unsigned short* w1t = (unsigned short*)(ws + WS_W1T);
  unsigned short* w2t = (unsigned short*)(ws + WS_W2T);
  float* bias1 = (float*)(ws + WS_B1);
  float* bias2 = (float*)(ws + WS_B2);

  prep_w1<<<A_ * 64, 256, 0, stream>>>(w1, routing, w1t);
  prep_w2<<<A_ * 8, 256, 0, stream>>>(w2, routing, w2t);
  prep_bias<<<A_, 512, 0, stream>>>(w1, b1, b2, routing, bias1, bias2);
  divtree_main<<<A_ * (B_ / BM_), 512, 0, stream>>>(x, w1t, w2t, bias1, bias2,
                                                    out);
}